// Round 3
// baseline (332.374 us; speedup 1.0000x reference)
//
#include <hip/hip_runtime.h>
#include <hip/hip_bf16.h>

// EmbeddingRNN via MFMA, round 3.
//   phase 0a: embWp = pack(emb @ W + b)   (155 x 1024 f32, packed so each thread's
//             8 gate-values for one (w,l15) are contiguous -> 2x float4 gather)
//   phase 0b: Upack = U as bf16 MFMA B-fragments, wave-slice-major
//   phase 1:  256 blocks x 8 waves x 32 rows, all 16 steps fused.
//             h kept in LDS as bf16 (XOR-swizzled), double-buffered.
//             Per step: acc = gather(embWp[x_t]) ; acc += h @ U (MFMA) ; gates.

#define DD      256
#define G4      1024
#define NCHAR   155
#define TSTEPS  16
#define RTILE   32
#define NROWS   8192
#define NBLOCKS (NROWS / RTILE)   // 256
#define NTHREADS 512              // 8 waves; wave w owns d-slice [w*32, w*32+32)

typedef __attribute__((ext_vector_type(8))) short bf16x8;
typedef __attribute__((ext_vector_type(4))) float f32x4;

__device__ inline unsigned short f2bf_bits(float f) {
    __hip_bfloat16 h = __float2bfloat16(f);   // RTNE
    return *reinterpret_cast<unsigned short*>(&h);
}

// ---------------- phase 0a: embWp = pack(emb @ W + b) ----------------
// value (char i, gate g, col d): w=d>>5, l15=d&15, nn=(d>>4)&1, nt=g*2+nn
// embWp[ ((i*8 + w)*16 + l15)*8 + nt ]
__global__ __launch_bounds__(256)
void embw_kernel(const float* __restrict__ emb, const float* __restrict__ W,
                 const float* __restrict__ b, float* __restrict__ embWp) {
    const int i   = blockIdx.x;      // 0..154
    const int tid = threadIdx.x;     // owns col d = tid, all 4 gates
    float a0 = b[tid], a1 = b[256 + tid], a2 = b[512 + tid], a3 = b[768 + tid];
    const float* er = emb + i * DD;
    for (int k = 0; k < DD; ++k) {
        const float e = er[k];
        const float* wr = W + k * G4 + tid;
        a0 += e * wr[0];
        a1 += e * wr[256];
        a2 += e * wr[512];
        a3 += e * wr[768];
    }
    const int w = tid >> 5, l15 = tid & 15, nn = (tid >> 4) & 1;
    float* o = embWp + ((i * 8 + w) * 16 + l15) * 8 + nn;
    o[0] = a0; o[2] = a1; o[4] = a2; o[6] = a3;   // nt = g*2+nn
}

// ---------------- phase 0b: pack U into bf16 MFMA B-fragments ----------------
// up[((w*8 + kt)*8 + nt)*64 + lane]: lane l holds U[kt*32+(l>>4)*8+j][g*256+w*32+nn*16+(l&15)]
__global__ __launch_bounds__(256)
void upack_kernel(const float* __restrict__ U, bf16x8* __restrict__ up) {
    const int gid  = blockIdx.x * 256 + threadIdx.x;   // 32768 total
    const int lane = gid & 63;
    const int nt   = (gid >> 6) & 7;
    const int kt   = (gid >> 9) & 7;
    const int w    = gid >> 12;
    const int g = nt >> 1, nn = nt & 1;
    const int col = g * 256 + w * 32 + nn * 16 + (lane & 15);
    const int k0  = kt * 32 + (lane >> 4) * 8;
    bf16x8 v;
#pragma unroll
    for (int j = 0; j < 8; ++j) v[j] = (short)f2bf_bits(U[(k0 + j) * G4 + col]);
    up[gid] = v;
}

// ---------------- phase 1: fused recurrence ----------------
__global__ __launch_bounds__(NTHREADS, 2)
void lstm_mfma(const int* __restrict__ x, const float* __restrict__ embWp,
               const bf16x8* __restrict__ up, float* __restrict__ out) {
    // h double-buffered bf16, byte-XOR swizzle ^((row&7)<<4):
    //  - A-read ds_read_b128 (16B, 16B-aligned, XOR hits bits 4-6 only) conflict-free-ish
    //  - gate-phase b16 writes 2-way max
    __shared__ __align__(16) unsigned short hb[2][RTILE * DD];  // 2 x 16KB
    __shared__ int xs[RTILE * TSTEPS];                          // 2KB

    const int tid  = threadIdx.x;
    const int w    = tid >> 6;
    const int lane = tid & 63;
    const int l15  = lane & 15, lg = lane >> 4;
    const int base = blockIdx.x * RTILE;

    xs[tid] = x[base * TSTEPS + tid];

    f32x4 acc[2][8];
    float c[16];
#pragma unroll
    for (int i = 0; i < 16; ++i) c[i] = 0.f;

    const bf16x8* upw = up + w * 4096;   // this wave's 64KB packed U slice

    __syncthreads();

    for (int t = 0; t < TSTEPS; ++t) {
        // ---- acc init: z = embW[x_t] gather (+b folded in), 2x float4 per (mt,j) ----
#pragma unroll
        for (int mt = 0; mt < 2; ++mt) {
#pragma unroll
            for (int j = 0; j < 4; ++j) {
                const int r    = mt * 16 + lg * 4 + j;        // C/D row
                const int xrow = xs[r * TSTEPS + t];
                const float4* ew =
                    (const float4*)(embWp + ((xrow * 8 + w) * 16 + l15) * 8);
                const float4 g0 = ew[0];
                const float4 g1 = ew[1];
                acc[mt][0][j] = g0.x; acc[mt][1][j] = g0.y;
                acc[mt][2][j] = g0.z; acc[mt][3][j] = g0.w;
                acc[mt][4][j] = g1.x; acc[mt][5][j] = g1.y;
                acc[mt][6][j] = g1.z; acc[mt][7][j] = g1.w;
            }
        }

        // ---- z += h @ U via MFMA (skip at t=0: h=0) ----
        if (t > 0) {
            const char* rb = (const char*)hb[(t - 1) & 1];
#pragma unroll
            for (int kt = 0; kt < 8; ++kt) {
                bf16x8 bfr[8];
#pragma unroll
                for (int nt = 0; nt < 8; ++nt)
                    bfr[nt] = upw[(kt * 8 + nt) * 64 + lane];  // 1KB/instr, L2

                bf16x8 afr[2];
#pragma unroll
                for (int mt = 0; mt < 2; ++mt) {
                    const int row = mt * 16 + l15;             // A row = lane&15
                    const int off = (row * 512 + kt * 64 + lg * 16) ^ ((row & 7) << 4);
                    afr[mt] = *(const bf16x8*)(rb + off);      // ds_read_b128
                }
#pragma unroll
                for (int mt = 0; mt < 2; ++mt)
#pragma unroll
                    for (int nt = 0; nt < 8; ++nt)
                        acc[mt][nt] = __builtin_amdgcn_mfma_f32_16x16x32_bf16(
                            afr[mt], bfr[nt], acc[mt][nt], 0, 0, 0);
            }
        }

        // ---- gate update (Keras i,f,g,o; identity candidate/output) ----
        char* wb = (char*)hb[t & 1];
#pragma unroll
        for (int mt = 0; mt < 2; ++mt) {
#pragma unroll
            for (int nn = 0; nn < 2; ++nn) {
#pragma unroll
                for (int j = 0; j < 4; ++j) {
                    const float zi = acc[mt][0 + nn][j];
                    const float zf = acc[mt][2 + nn][j];
                    const float zg = acc[mt][4 + nn][j];
                    const float zo = acc[mt][6 + nn][j];
                    const float ig = 1.f / (1.f + __expf(-zi));
                    const float fg = 1.f / (1.f + __expf(-zf));
                    const float og = 1.f / (1.f + __expf(-zo));
                    const int   ci = mt * 8 + nn * 4 + j;
                    const float cn = fg * c[ci] + ig * zg;
                    c[ci] = cn;
                    const float h = og * cn;
                    const int row = mt * 16 + lg * 4 + j;
                    const int d   = w * 32 + nn * 16 + l15;
                    const int off = (row * 512 + d * 2) ^ ((row & 7) << 4);
                    *(unsigned short*)(wb + off) = f2bf_bits(h);
                    if (t == TSTEPS - 1) out[(base + row) * DD + d] = h;
                }
            }
        }
        __syncthreads();   // h(t) visible; prev-buffer reads done
    }
}

extern "C" void kernel_launch(void* const* d_in, const int* in_sizes, int n_in,
                              void* d_out, int out_size, void* d_ws, size_t ws_size,
                              hipStream_t stream) {
    const int*   x   = (const int*)d_in[0];
    const float* emb = (const float*)d_in[1];
    const float* W   = (const float*)d_in[2];
    const float* U   = (const float*)d_in[3];
    const float* b   = (const float*)d_in[4];
    float* out = (float*)d_out;

    float*  embWp = (float*)d_ws;                          // 620KB
    bf16x8* up    = (bf16x8*)((char*)d_ws + (1 << 20));    // 512KB at +1MB

    embw_kernel<<<NCHAR, 256, 0, stream>>>(emb, W, b, embWp);
    upack_kernel<<<128, 256, 0, stream>>>(U, up);
    lstm_mfma<<<NBLOCKS, NTHREADS, 0, stream>>>(x, embWp, up, out);
}